// Round 1
// baseline (946.553 us; speedup 1.0000x reference)
//
#include <hip/hip_runtime.h>
#include <hip/hip_bf16.h>

// Problem constants
#define M_ROWS 4096
#define N_OUT  1024
#define K_IN   1024
#define MASK_N 134217728   // 512^3

// ---------- fp32 -> bf16 round-to-nearest-even ----------
__device__ inline short f2bf(float f) {
    unsigned u = __float_as_uint(f);
    unsigned r = u + 0x7fffu + ((u >> 16) & 1u);
    return (short)(r >> 16);
}

__device__ inline float next_up(float f) {
    unsigned u = __float_as_uint(f);
    if (u == 0x80000000u || u == 0u) return __uint_as_float(0x00000001u);
    if (f > 0.0f) return __uint_as_float(u + 1u);
    return __uint_as_float(u - 1u);
}

// ---------- Kernel 1: column sums of input and weight (fp64 partials) ----------
// blocks 0..31: input rows chunked by 128; blocks 32..39: weight rows chunked by 128.
// thread t covers columns {t, t+256, t+512, t+768} (coalesced per row).
__global__ __launch_bounds__(256) void colsum_kernel(
    const float* __restrict__ input, const float* __restrict__ weight,
    double* __restrict__ s_in, double* __restrict__ w_sum)
{
    int b = blockIdx.x;
    int t = threadIdx.x;
    const float* src;
    double* dst;
    int row0;
    if (b < 32) { src = input;  dst = s_in;  row0 = b * 128; }
    else        { src = weight; dst = w_sum; row0 = (b - 32) * 128; }
    for (int c = 0; c < 4; ++c) {
        int col = t + c * 256;
        double acc = 0.0;
        for (int r = 0; r < 128; ++r)
            acc += (double)src[(size_t)(row0 + r) * 1024 + col];
        atomicAdd(&dst[col], acc);
    }
}

// ---------- Kernel 2: combine to scalar threshold + exact float cut ----------
// threshold = (sum_i s_in[i]*w_sum[i])/4096 + sum_o bias[o]
__global__ __launch_bounds__(1024) void threshold_kernel(
    const double* __restrict__ s_in, const double* __restrict__ w_sum,
    const float* __restrict__ bias, double* __restrict__ thr, float* __restrict__ cut)
{
    __shared__ double red[1024];
    int t = threadIdx.x;
    double v = s_in[t] * w_sum[t] * (1.0 / 4096.0) + (double)bias[t];
    red[t] = v;
    __syncthreads();
    for (int s = 512; s > 0; s >>= 1) {
        if (t < s) red[t] += red[t + s];
        __syncthreads();
    }
    if (t == 0) {
        double th = red[0];
        *thr = th;
        float f = (float)th;
        if ((double)f <= th) f = next_up(f);
        // f is now the smallest float whose double value is > th:
        // (mask_float >= f)  <=>  (double)mask_float > th
        *cut = f;
    }
}

// ---------- Kernel 3: bf16 MFMA GEMM, 128x128 tile, BK=32 ----------
// out[m][n] = sum_k input[m][k] * weight[n][k] + bias[n]
// A-frag (16x16x32): lane holds A[m=lane&15][k=(lane>>4)*8+j], j=0..7
// B-frag:            lane holds W[n=lane&15][k=(lane>>4)*8+j]
// C/D: col = lane&15, row = (lane>>4)*4 + reg
typedef __attribute__((ext_vector_type(8))) short bf16x8;
typedef __attribute__((ext_vector_type(4))) float f32x4;

#define LDA 40   // 32 + 8 pad (bf16 elems); row stride 80 B (16B-aligned, conflict-friendly)

__global__ __launch_bounds__(256) void gemm_kernel(
    const float* __restrict__ A,     // input [4096][1024]
    const float* __restrict__ W,     // weight [1024][1024]
    const float* __restrict__ bias,
    float* __restrict__ C)           // out [4096][1024]
{
    __shared__ short As[128 * LDA];
    __shared__ short Bs[128 * LDA];

    const int tid  = threadIdx.x;
    const int wave = tid >> 6;
    const int lane = tid & 63;
    const int quad = lane >> 4;
    const int l16  = lane & 15;
    const int wr   = (wave >> 1) * 64;   // wave row offset in 128-tile
    const int wc   = (wave & 1) * 64;    // wave col offset

    const int tile_m = (blockIdx.x >> 3) * 128;  // 32 row tiles
    const int tile_n = (blockIdx.x & 7) * 128;   // 8 col tiles

    f32x4 acc[4][4];
    for (int i = 0; i < 4; ++i)
        for (int j = 0; j < 4; ++j)
            acc[i][j] = (f32x4){0.f, 0.f, 0.f, 0.f};

    for (int k0 = 0; k0 < K_IN; k0 += 32) {
        // stage 128x32 of A and of W as bf16. 1024 float4 per matrix; 4 per thread.
        for (int it = 0; it < 4; ++it) {
            int f   = tid + it * 256;
            int row = f >> 3;           // 0..127
            int c4  = (f & 7) << 2;     // 0..28 step 4
            float4 av = *(const float4*)&A[(size_t)(tile_m + row) * K_IN + k0 + c4];
            float4 bv = *(const float4*)&W[(size_t)(tile_n + row) * K_IN + k0 + c4];
            short4 a4 = { f2bf(av.x), f2bf(av.y), f2bf(av.z), f2bf(av.w) };
            short4 b4 = { f2bf(bv.x), f2bf(bv.y), f2bf(bv.z), f2bf(bv.w) };
            *(short4*)&As[row * LDA + c4] = a4;
            *(short4*)&Bs[row * LDA + c4] = b4;
        }
        __syncthreads();

        bf16x8 af[4], bfr[4];
        for (int i = 0; i < 4; ++i) {
            af[i]  = *(const bf16x8*)&As[(wr + i * 16 + l16) * LDA + quad * 8];
            bfr[i] = *(const bf16x8*)&Bs[(wc + i * 16 + l16) * LDA + quad * 8];
        }
        for (int i = 0; i < 4; ++i)
            for (int j = 0; j < 4; ++j)
                acc[i][j] = __builtin_amdgcn_mfma_f32_16x16x32_bf16(
                    af[i], bfr[j], acc[i][j], 0, 0, 0);
        __syncthreads();
    }

    // epilogue: add bias, store fp32
    for (int i = 0; i < 4; ++i) {
        for (int j = 0; j < 4; ++j) {
            int col = tile_n + wc + j * 16 + l16;
            float b = bias[col];
            for (int r = 0; r < 4; ++r) {
                int row = tile_m + wr + i * 16 + quad * 4 + r;
                C[(size_t)row * N_OUT + col] = acc[i][j][r] + b;
            }
        }
    }
}

// ---------- Kernel 4: mask > threshold, vectorized float4 ----------
__global__ __launch_bounds__(256) void mask_kernel(
    const float4* __restrict__ mask, float4* __restrict__ out,
    const float* __restrict__ cut_p, int n4)
{
    float cut = *cut_p;
    int i = blockIdx.x * blockDim.x + threadIdx.x;
    int stride = gridDim.x * blockDim.x;
    for (; i < n4; i += stride) {
        float4 m = mask[i];
        float4 o;
        o.x = (m.x >= cut) ? 1.0f : 0.0f;
        o.y = (m.y >= cut) ? 1.0f : 0.0f;
        o.z = (m.z >= cut) ? 1.0f : 0.0f;
        o.w = (m.w >= cut) ? 1.0f : 0.0f;
        out[i] = o;
    }
}

extern "C" void kernel_launch(void* const* d_in, const int* in_sizes, int n_in,
                              void* d_out, int out_size, void* d_ws, size_t ws_size,
                              hipStream_t stream) {
    const float* input  = (const float*)d_in[0];   // [4096,1024]
    const float* mask   = (const float*)d_in[1];   // [512,512,512]
    const float* weight = (const float*)d_in[2];   // [1024,1024]
    const float* bias   = (const float*)d_in[3];   // [1024]

    float* out = (float*)d_out;                          // [4096,1024]
    float* hi  = out + (size_t)M_ROWS * N_OUT;           // [512^3] as 0/1 floats

    double* s_in  = (double*)d_ws;         // 1024 doubles
    double* w_sum = s_in + 1024;           // 1024 doubles
    double* thr   = w_sum + 1024;          // 1 double
    float*  cut   = (float*)(thr + 1);     // 1 float

    // zero the fp64 accumulators (ws is poisoned 0xAA before every launch)
    hipMemsetAsync(d_ws, 0, 2048 * sizeof(double), stream);

    colsum_kernel<<<40, 256, 0, stream>>>(input, weight, s_in, w_sum);
    threshold_kernel<<<1, 1024, 0, stream>>>(s_in, w_sum, bias, thr, cut);
    gemm_kernel<<<256, 256, 0, stream>>>(input, weight, bias, out);
    mask_kernel<<<16384, 256, 0, stream>>>((const float4*)mask, (float4*)hi,
                                           cut, MASK_N / 4);
}

// Round 2
// 904.298 us; speedup vs baseline: 1.0467x; 1.0467x over previous
//
#include <hip/hip_runtime.h>
#include <hip/hip_bf16.h>
#include <stdint.h>

// Problem constants
#define M_ROWS 4096
#define N_OUT  1024
#define K_IN   1024
#define MASK_N 134217728   // 512^3

typedef __attribute__((ext_vector_type(8))) short bf16x8;
typedef __attribute__((ext_vector_type(4))) float f32x4;
typedef float f4v __attribute__((ext_vector_type(4)));

// ---------- fp32 -> bf16 round-to-nearest-even ----------
__device__ inline short f2bf(float f) {
    unsigned u = __float_as_uint(f);
    unsigned r = u + 0x7fffu + ((u >> 16) & 1u);
    return (short)(r >> 16);
}

__device__ inline float next_up(float f) {
    unsigned u = __float_as_uint(f);
    if (u == 0x80000000u || u == 0u) return __uint_as_float(0x00000001u);
    if (f > 0.0f) return __uint_as_float(u + 1u);
    return __uint_as_float(u - 1u);
}

// 16B global -> LDS async DMA (wave-uniform base + lane*16 on the LDS side)
__device__ inline void async16(const void* g, void* l) {
    __builtin_amdgcn_global_load_lds(
        (const __attribute__((address_space(1))) unsigned int*)g,
        (__attribute__((address_space(3))) unsigned int*)l, 16, 0, 0);
}

// ---------- Kernel 1: fused fp32->bf16 convert (XOR-swizzled layout) + column sums ----------
// blocks 0..255  : input rows 16b..16b+15
// blocks 256..319: weight rows 16(b-256)..+15
// thread t owns cols 4t..4t+3 (float4 read, short4 swizzled write, fp64 col partials)
// Swizzle: orig element (R, kc*32 + c*8 + j) stored at col kc*32 + (c ^ ((R>>1)&3))*8 + j.
__global__ __launch_bounds__(256) void conv_colsum_kernel(
    const float* __restrict__ input, const float* __restrict__ weight,
    short* __restrict__ in_bf, short* __restrict__ w_bf,
    double* __restrict__ s_in, double* __restrict__ w_sum)
{
    int b = blockIdx.x;
    int t = threadIdx.x;
    const float* src; short* dst; double* sums; int row0;
    if (b < 256) { src = input;  dst = in_bf; sums = s_in;  row0 = b * 16; }
    else         { src = weight; dst = w_bf;  sums = w_sum; row0 = (b - 256) * 16; }

    const int kc = t >> 3;          // 32-col block
    const int c  = (t >> 1) & 3;    // 8-col chunk within block
    const int j0 = (t & 1) << 2;    // 4-col half within chunk

    double a0 = 0, a1 = 0, a2 = 0, a3 = 0;
    for (int r = 0; r < 16; ++r) {
        int R = row0 + r;
        float4 v = *(const float4*)&src[(size_t)R * 1024 + 4 * t];
        int sc = c ^ ((R >> 1) & 3);
        short4 s4 = { f2bf(v.x), f2bf(v.y), f2bf(v.z), f2bf(v.w) };
        *(short4*)&dst[(size_t)R * 1024 + (kc << 5) + (sc << 3) + j0] = s4;
        a0 += (double)v.x; a1 += (double)v.y; a2 += (double)v.z; a3 += (double)v.w;
    }
    int c0 = 4 * t;
    atomicAdd(&sums[c0 + 0], a0);
    atomicAdd(&sums[c0 + 1], a1);
    atomicAdd(&sums[c0 + 2], a2);
    atomicAdd(&sums[c0 + 3], a3);
}

// ---------- Kernel 2: combine to scalar threshold + exact float cut ----------
// threshold = (sum_i s_in[i]*w_sum[i])/4096 + sum_o bias[o]
__global__ __launch_bounds__(1024) void threshold_kernel(
    const double* __restrict__ s_in, const double* __restrict__ w_sum,
    const float* __restrict__ bias, double* __restrict__ thr, float* __restrict__ cut)
{
    __shared__ double red[1024];
    int t = threadIdx.x;
    double v = s_in[t] * w_sum[t] * (1.0 / 4096.0) + (double)bias[t];
    red[t] = v;
    __syncthreads();
    for (int s = 512; s > 0; s >>= 1) {
        if (t < s) red[t] += red[t + s];
        __syncthreads();
    }
    if (t == 0) {
        double th = red[0];
        *thr = th;
        float f = (float)th;
        if ((double)f <= th) f = next_up(f);
        // f = smallest float with (double)f > th:  (m >= f) <=> ((double)m > th)
        *cut = f;
    }
}

// ---------- Kernel 3: bf16 MFMA GEMM (m97 structure), 128x128 tile, BK=32 ----------
// Inputs are pre-converted bf16 in the swizzled layout; staging via global_load_lds x16B.
// A-frag (16x16x32): lane holds A[m=lane&15][k=quad*8+j]; C/D: col=lane&15, row=quad*4+reg.
__global__ __launch_bounds__(256) void gemm_kernel(
    const short* __restrict__ Abf,   // input bf16 [4096][1024] swizzled
    const short* __restrict__ Wbf,   // weight bf16 [1024][1024] swizzled
    const float* __restrict__ bias,
    float* __restrict__ C)           // out fp32 [4096][1024]
{
    __shared__ short As[128 * 32];   // 8 KB, no padding (DMA constraint); XOR swizzle in layout
    __shared__ short Bs[128 * 32];

    const int tid  = threadIdx.x;
    const int wave = tid >> 6;
    const int lane = tid & 63;
    const int quad = lane >> 4;
    const int l16  = lane & 15;
    const int wr   = (wave >> 1) * 64;
    const int wc   = (wave & 1) * 64;

    const int tile_m = (blockIdx.x >> 3) * 128;  // 32 row tiles
    const int tile_n = (blockIdx.x & 7) * 128;   // 8 col tiles

    f32x4 acc[4][4];
    for (int i = 0; i < 4; ++i)
        for (int j = 0; j < 4; ++j)
            acc[i][j] = (f32x4){0.f, 0.f, 0.f, 0.f};

    // staging addresses: thread tid covers row tid>>2 (+64 for 2nd issue), chunk tid&3
    const short* gA = Abf + (size_t)(tile_m + (tid >> 2)) * 1024 + ((tid & 3) << 3);
    const short* gB = Wbf + (size_t)(tile_n + (tid >> 2)) * 1024 + ((tid & 3) << 3);
    short* lA = &As[tid * 8];     // per-wave linear: base + lane*16 B
    short* lB = &Bs[tid * 8];

    for (int k0 = 0; k0 < K_IN; k0 += 32) {
        async16(gA + k0,             lA);
        async16(gA + 64 * 1024 + k0, lA + 64 * 32);
        async16(gB + k0,             lB);
        async16(gB + 64 * 1024 + k0, lB + 64 * 32);
        __syncthreads();   // compiler emits vmcnt(0) drain before barrier

        bf16x8 af[4], bfr[4];
        for (int i = 0; i < 4; ++i) {
            int ra = wr + i * 16 + l16;
            af[i]  = *(const bf16x8*)&As[ra * 32 + ((quad ^ ((ra >> 1) & 3)) << 3)];
            int rb = wc + i * 16 + l16;
            bfr[i] = *(const bf16x8*)&Bs[rb * 32 + ((quad ^ ((rb >> 1) & 3)) << 3)];
        }
        for (int i = 0; i < 4; ++i)
            for (int j = 0; j < 4; ++j)
                acc[i][j] = __builtin_amdgcn_mfma_f32_16x16x32_bf16(
                    af[i], bfr[j], acc[i][j], 0, 0, 0);
        __syncthreads();
    }

    for (int i = 0; i < 4; ++i) {
        for (int j = 0; j < 4; ++j) {
            int col = tile_n + wc + j * 16 + l16;
            float b = bias[col];
            for (int r = 0; r < 4; ++r) {
                int row = tile_m + wr + i * 16 + quad * 4 + r;
                C[(size_t)row * N_OUT + col] = acc[i][j][r] + b;
            }
        }
    }
}

// ---------- Kernel 4: mask >= cut, float4 non-temporal stream ----------
__global__ __launch_bounds__(256) void mask_kernel(
    const f4v* __restrict__ mask, f4v* __restrict__ out,
    const float* __restrict__ cut_p, int n4)
{
    float cut = *cut_p;
    int i = blockIdx.x * blockDim.x + threadIdx.x;
    int stride = gridDim.x * blockDim.x;
    for (; i < n4; i += stride) {
        f4v m = __builtin_nontemporal_load(&mask[i]);
        f4v o;
        o.x = (m.x >= cut) ? 1.0f : 0.0f;
        o.y = (m.y >= cut) ? 1.0f : 0.0f;
        o.z = (m.z >= cut) ? 1.0f : 0.0f;
        o.w = (m.w >= cut) ? 1.0f : 0.0f;
        __builtin_nontemporal_store(o, &out[i]);
    }
}

extern "C" void kernel_launch(void* const* d_in, const int* in_sizes, int n_in,
                              void* d_out, int out_size, void* d_ws, size_t ws_size,
                              hipStream_t stream) {
    const float* input  = (const float*)d_in[0];   // [4096,1024]
    const float* mask   = (const float*)d_in[1];   // [512,512,512]
    const float* weight = (const float*)d_in[2];   // [1024,1024]
    const float* bias   = (const float*)d_in[3];   // [1024]

    float* out = (float*)d_out;                          // [4096,1024]
    float* hi  = out + (size_t)M_ROWS * N_OUT;           // [512^3] as 0/1 floats

    // workspace layout (bytes):
    //   0      : s_in   [1024] double  (8 KB)
    //   8192   : w_sum  [1024] double  (8 KB)
    //   16384  : thr (double), cut (float)
    //   32768  : in_bf  [4096*1024] bf16 (8 MB)
    //   8421376: w_bf   [1024*1024] bf16 (2 MB)
    char* wsb = (char*)d_ws;
    double* s_in  = (double*)wsb;
    double* w_sum = (double*)(wsb + 8192);
    double* thr   = (double*)(wsb + 16384);
    float*  cut   = (float*)(wsb + 16384 + 8);
    short*  in_bf = (short*)(wsb + 32768);
    short*  w_bf  = (short*)(wsb + 32768 + (size_t)M_ROWS * K_IN * 2);

    // zero the fp64 accumulators (ws is poisoned 0xAA before every launch)
    hipMemsetAsync(d_ws, 0, 16384, stream);

    conv_colsum_kernel<<<320, 256, 0, stream>>>(input, weight, in_bf, w_bf, s_in, w_sum);
    threshold_kernel<<<1, 1024, 0, stream>>>(s_in, w_sum, bias, thr, cut);
    gemm_kernel<<<256, 256, 0, stream>>>(in_bf, w_bf, bias, out);
    mask_kernel<<<16384, 256, 0, stream>>>((const f4v*)mask, (f4v*)hi, cut, MASK_N / 4);
}